// Round 2
// baseline (2054.064 us; speedup 1.0000x reference)
//
#include <hip/hip_runtime.h>
#include <hip/hip_bf16.h>
#include <math.h>

// Problem constants
#define NUM_ENTITIES 50000
#define NUM_RELS 200
#define REL_DIM 128
#define COMB_DIM 256
#define N_NODES 20000
#define NE 4096
#define IN_DIM 512
#define HID 1024

typedef __attribute__((ext_vector_type(8))) short bf16x8;
typedef __attribute__((ext_vector_type(4))) float f32x4;

static __device__ __forceinline__ short f2bf(float f) {
    union { float f; unsigned u; } v; v.f = f;
    unsigned r = v.u + 0x7fff + ((v.u >> 16) & 1);   // RNE
    return (short)(r >> 16);
}

// ---------------------------------------------------------------------------
// Gather + concat + bf16 cast: emb[e][c], e<4096, c<512
__global__ __launch_bounds__(256) void gather_emb(
    const float* __restrict__ comb, const float* __restrict__ rel,
    const float* __restrict__ dyn, const int* __restrict__ edge_index,
    const int* __restrict__ edge_type, short* __restrict__ embB)
{
    int idx = blockIdx.x * 256 + threadIdx.x;      // 4096*512 total
    if (idx >= NE * IN_DIM) return;
    int e = idx >> 9;
    int c = idx & 511;
    int head = edge_index[e];                      // row 0 of (2,E)
    int et   = edge_type[e];
    float val;
    if (c < COMB_DIM)            val = comb[head * COMB_DIM + c];
    else if (c < COMB_DIM + REL_DIM) val = rel[et * REL_DIM + (c - COMB_DIM)];
    else                         val = dyn[((et * 4 + 3) * REL_DIM + (c - 384)) * 2 + 1];
    embB[idx] = f2bf(val);
}

// ---------------------------------------------------------------------------
// Transpose + cast: in fp32 [K][N] row-major -> out bf16 [N][K]
__global__ __launch_bounds__(256) void transpose_cast(
    const float* __restrict__ in, short* __restrict__ out, int K, int N)
{
    __shared__ float tile[32][33];
    int bx = blockIdx.x, by = blockIdx.y;
    int tx = threadIdx.x, ty = threadIdx.y;        // 32 x 8
    int x = bx * 32 + tx;
    #pragma unroll
    for (int i = 0; i < 4; i++) {
        int y = by * 32 + ty + i * 8;
        float v = 0.f;
        if (x < N) v = in[(size_t)y * N + x];
        tile[ty + i * 8][tx] = v;
    }
    __syncthreads();
    int k = by * 32 + tx;
    #pragma unroll
    for (int i = 0; i < 4; i++) {
        int n = bx * 32 + ty + i * 8;
        if (n < N) out[(size_t)n * K + k] = f2bf(tile[tx][ty + i * 8]);
    }
}

// ---------------------------------------------------------------------------
// MFMA GEMM: C[M,N] = A[M,K] @ Bt[N,K]^T (+bias). 128x128 tile, BK=32,
// 4 waves (2x2), each wave 64x64 = 4x4 16x16x32 fragments.
// TANH=1: store bf16 tanh(C) to Ch (row stride N). TANH=0: store fp32 to Cf.
template<int TANH>
__global__ __launch_bounds__(256) void gemm_bf16(
    const short* __restrict__ A, const short* __restrict__ Bt,
    const float* __restrict__ bias, float* __restrict__ Cf,
    short* __restrict__ Ch, int N, int K)
{
    __shared__ short As[128][32];
    __shared__ short Bs[128][32];
    const int tid  = threadIdx.x;
    const int lane = tid & 63;
    const int w    = tid >> 6;
    const int wr   = w >> 1, wc = w & 1;
    const int mbase = blockIdx.x * 128;
    const int nbase = blockIdx.y * 128;

    f32x4 acc[4][4];
    #pragma unroll
    for (int m = 0; m < 4; m++)
        #pragma unroll
        for (int n = 0; n < 4; n++)
            acc[m][n] = (f32x4){0.f, 0.f, 0.f, 0.f};

    const int srow = tid >> 1;
    const int skc  = (tid & 1) * 16;
    const size_t aoff = (size_t)(mbase + srow) * K + skc;
    const int    brow = nbase + srow;
    const bool   bok  = brow < N;
    const size_t boff = (size_t)brow * K + skc;
    const bf16x8 zed = {0,0,0,0,0,0,0,0};

    for (int k0 = 0; k0 < K; k0 += 32) {
        bf16x8 av0 = *(const bf16x8*)(A + aoff + k0);
        bf16x8 av1 = *(const bf16x8*)(A + aoff + k0 + 8);
        bf16x8 bv0 = bok ? *(const bf16x8*)(Bt + boff + k0) : zed;
        bf16x8 bv1 = bok ? *(const bf16x8*)(Bt + boff + k0 + 8) : zed;
        __syncthreads();
        *(bf16x8*)&As[srow][skc]     = av0;
        *(bf16x8*)&As[srow][skc + 8] = av1;
        *(bf16x8*)&Bs[srow][skc]     = bv0;
        *(bf16x8*)&Bs[srow][skc + 8] = bv1;
        __syncthreads();

        bf16x8 af[4], bff[4];
        #pragma unroll
        for (int m = 0; m < 4; m++)
            af[m] = *(const bf16x8*)&As[wr * 64 + m * 16 + (lane & 15)][(lane >> 4) * 8];
        #pragma unroll
        for (int n = 0; n < 4; n++)
            bff[n] = *(const bf16x8*)&Bs[wc * 64 + n * 16 + (lane & 15)][(lane >> 4) * 8];
        #pragma unroll
        for (int m = 0; m < 4; m++)
            #pragma unroll
            for (int n = 0; n < 4; n++)
                acc[m][n] = __builtin_amdgcn_mfma_f32_16x16x32_bf16(af[m], bff[n], acc[m][n], 0, 0, 0);
    }

    const int r0 = (lane >> 4) * 4;
    const int c0 = lane & 15;
    #pragma unroll
    for (int m = 0; m < 4; m++) {
        #pragma unroll
        for (int n = 0; n < 4; n++) {
            int col = nbase + wc * 64 + n * 16 + c0;
            if (col < N) {
                float bv = bias[col];
                #pragma unroll
                for (int j = 0; j < 4; j++) {
                    int row = mbase + wr * 64 + m * 16 + r0 + j;
                    float v = acc[m][n][j] + bv;
                    if (TANH) Ch[(size_t)row * N + col] = f2bf(tanhf(v));
                    else      Cf[(size_t)row * N + col] = v;
                }
            }
        }
    }
}

// ---------------------------------------------------------------------------
// Per-row logZ = max + log(sum exp(x - max)); one block per row.
__global__ __launch_bounds__(256) void row_logz(
    const float* __restrict__ tp, float* __restrict__ logZ)
{
    const int row = blockIdx.x;
    const float* x = tp + (size_t)row * NUM_ENTITIES;
    __shared__ float red[4];

    float m = -1e30f;
    for (int i = threadIdx.x; i < NUM_ENTITIES; i += 256)
        m = fmaxf(m, x[i]);
    #pragma unroll
    for (int off = 32; off; off >>= 1) m = fmaxf(m, __shfl_xor(m, off));
    if ((threadIdx.x & 63) == 0) red[threadIdx.x >> 6] = m;
    __syncthreads();
    float bm = fmaxf(fmaxf(red[0], red[1]), fmaxf(red[2], red[3]));
    __syncthreads();

    float s = 0.f;
    for (int i = threadIdx.x; i < NUM_ENTITIES; i += 256)
        s += __expf(x[i] - bm);
    #pragma unroll
    for (int off = 32; off; off >>= 1) s += __shfl_xor(s, off);
    if ((threadIdx.x & 63) == 0) red[threadIdx.x >> 6] = s;
    __syncthreads();
    if (threadIdx.x == 0)
        logZ[row] = bm + logf(red[0] + red[1] + red[2] + red[3]);
}

// ---------------------------------------------------------------------------
// mean over edges of (tp[e, label_e] - logZ[e]) -> out0[0]
__global__ __launch_bounds__(256) void final_mean(
    const float* __restrict__ tp, const float* __restrict__ logZ,
    const int* __restrict__ target_tails, const int* __restrict__ node_id,
    float* __restrict__ out0)
{
    __shared__ float red[4];
    float s = 0.f;
    for (int e = threadIdx.x; e < NE; e += 256) {
        int lbl = node_id[target_tails[e]];
        s += tp[(size_t)e * NUM_ENTITIES + lbl] - logZ[e];
    }
    #pragma unroll
    for (int off = 32; off; off >>= 1) s += __shfl_xor(s, off);
    if ((threadIdx.x & 63) == 0) red[threadIdx.x >> 6] = s;
    __syncthreads();
    if (threadIdx.x == 0)
        out0[0] = (red[0] + red[1] + red[2] + red[3]) * (1.0f / (float)NE);
}

// ---------------------------------------------------------------------------
extern "C" void kernel_launch(void* const* d_in, const int* in_sizes, int n_in,
                              void* d_out, int out_size, void* d_ws, size_t ws_size,
                              hipStream_t stream) {
    const float* comb = (const float*)d_in[0];
    const float* rel  = (const float*)d_in[1];
    const float* dyn  = (const float*)d_in[2];
    const float* W1   = (const float*)d_in[3];
    const float* b1   = (const float*)d_in[4];
    const float* W2   = (const float*)d_in[5];
    const float* b2   = (const float*)d_in[6];
    const int* edge_index   = (const int*)d_in[7];
    const int* edge_type    = (const int*)d_in[8];
    const int* target_tails = (const int*)d_in[9];
    const int* node_id      = (const int*)d_in[10];

    float* out = (float*)d_out;

    char* ws = (char*)d_ws;
    short* embB = (short*)ws;  ws += (size_t)NE * IN_DIM * 2;           // 4 MB
    short* W1T  = (short*)ws;  ws += (size_t)HID * IN_DIM * 2;          // 1 MB
    short* hB   = (short*)ws;  ws += (size_t)NE * HID * 2;              // 8 MB
    short* W2T  = (short*)ws;  ws += (size_t)NUM_ENTITIES * HID * 2;    // 100 MB
    float* logZ = (float*)ws;  ws += (size_t)NE * 4;

    // 1. gather + cast emb (4096 x 512 bf16)
    gather_emb<<<(NE * IN_DIM) / 256, 256, 0, stream>>>(comb, rel, dyn,
                                                        edge_index, edge_type, embB);
    // 2. W1 (512x1024) -> W1T (1024x512 bf16); W2 (1024x50000) -> W2T (50000x1024 bf16)
    transpose_cast<<<dim3(HID / 32, IN_DIM / 32), dim3(32, 8), 0, stream>>>(W1, W1T, IN_DIM, HID);
    transpose_cast<<<dim3((NUM_ENTITIES + 31) / 32, HID / 32), dim3(32, 8), 0, stream>>>(W2, W2T, HID, NUM_ENTITIES);
    // 3. h = tanh(emb @ W1 + b1)  (4096 x 1024, bf16)
    gemm_bf16<1><<<dim3(NE / 128, HID / 128), 256, 0, stream>>>(embB, W1T, b1, nullptr, hB, HID, IN_DIM);
    // 4. tail_pred = h @ W2 + b2  (4096 x 50000, fp32, at out+1)
    gemm_bf16<0><<<dim3(NE / 128, (NUM_ENTITIES + 127) / 128), 256, 0, stream>>>(hB, W2T, b2, out + 1, nullptr, NUM_ENTITIES, HID);
    // 5. per-row log-sum-exp
    row_logz<<<NE, 256, 0, stream>>>(out + 1, logZ);
    // 6. scalar: mean log-prob at labels
    final_mean<<<1, 256, 0, stream>>>(out + 1, logZ, target_tails, node_id, out);
}